// Round 7
// baseline (46847.971 us; speedup 1.0000x reference)
//
#include <hip/hip_runtime.h>
#include <math.h>

#define BS   16384
#define HID  1024
#define G4   4096
#define EMB  512
#define WVD  300
#define IND  812
#define VOC  258
#define NST  14

__device__ __forceinline__ double dsig(double x){ return 1.0/(1.0+exp(-x)); }
__device__ __forceinline__ double dtanh_(double x){
  double ax = fabs(x);
  double e = exp(-2.0*ax);
  double t = (1.0-e)/(1.0+e);
  return x < 0.0 ? -t : t;
}

// ---------------- E = emb @ W_ih[:, :512].T -> f64 [VOC][G4] ----------------
#define ETT 16
__global__ __launch_bounds__(256) void ekernel_f64(const float* __restrict__ emb,
                                                   const float* __restrict__ Wih,
                                                   double* __restrict__ E){
  __shared__ float elds[ETT][EMB];
  const int tid = threadIdx.x;
  const int n  = blockIdx.x*256 + tid;      // 0..4095
  const int t0 = blockIdx.y*ETT;
  #pragma unroll
  for (int i = 0; i < 8; ++i){
    int fi = tid + 256*i;
    int tt = fi >> 7;
    int kk = (fi & 127) << 2;
    float4 v = make_float4(0.f,0.f,0.f,0.f);
    if (t0+tt < VOC) v = *(const float4*)(emb + (size_t)(t0+tt)*EMB + kk);
    *(float4*)&elds[tt][kk] = v;
  }
  __syncthreads();
  double acc[ETT];
  #pragma unroll
  for (int tt=0;tt<ETT;++tt) acc[tt]=0.0;
  const float* wr = Wih + (size_t)n*IND;
  for (int k=0;k<EMB;k+=4){
    float4 w = *(const float4*)(wr + k);
    double w0=w.x, w1=w.y, w2=w.z, w3=w.w;
    #pragma unroll
    for (int tt=0;tt<ETT;++tt){
      float4 e = *(const float4*)&elds[tt][k];
      acc[tt] += (double)e.x*w0 + (double)e.y*w1 + (double)e.z*w2 + (double)e.w*w3;
    }
  }
  #pragma unroll
  for (int tt=0;tt<ETT;++tt){
    int t = t0+tt;
    if (t < VOC) E[(size_t)t*G4 + n] = acc[tt];
  }
}

// ---------------- base = wv @ Wih[:,512:].T + b_ih + b_hh -> f64 [R][G4] ----------------
// 128x128 tile, 8x8 f64 acc, both operands f32 in LDS (inputs are f32). K pad 320, BK=32.
__global__ __launch_bounds__(256) void base_v3(const float* __restrict__ wv,
                                               const float* __restrict__ Wih,
                                               const float* __restrict__ bih,
                                               const float* __restrict__ bhh,
                                               double* __restrict__ base){
  __shared__ float Al[32][132];
  __shared__ float Bl[32][132];
  const int tid = threadIdx.x;
  const int r0 = blockIdx.x*128, n0 = blockIdx.y*128;
  const int tx = tid & 15, ty = tid >> 4;
  double acc[8][8];
  #pragma unroll
  for (int i=0;i<8;++i)
    #pragma unroll
    for (int j=0;j<8;++j) acc[i][j]=0.0;

  const int ra = tid >> 1, kb16 = (tid & 1) * 16;
  for (int t = 0; t < 10; ++t){
    int k0 = t*32;
    #pragma unroll
    for (int j=0;j<16;++j){
      int k = k0 + kb16 + j;
      Al[kb16+j][ra] = (k < WVD) ? wv[(size_t)(r0+ra)*WVD + k] : 0.f;
      Bl[kb16+j][ra] = (k < WVD) ? Wih[(size_t)(n0+ra)*IND + EMB + k] : 0.f;
    }
    __syncthreads();
    #pragma unroll
    for (int k=0;k<32;++k){
      double av[8], bv[8];
      #pragma unroll
      for (int i=0;i<8;++i) av[i] = (double)Al[k][ty*8+i];
      #pragma unroll
      for (int j=0;j<8;++j) bv[j] = (double)Bl[k][tx + 16*j];
      #pragma unroll
      for (int i=0;i<8;++i)
        #pragma unroll
        for (int j=0;j<8;++j) acc[i][j] += av[i]*bv[j];
    }
    __syncthreads();
  }
  #pragma unroll
  for (int i=0;i<8;++i){
    int r = r0 + ty*8 + i;
    #pragma unroll
    for (int j=0;j<8;++j){
      int n = n0 + tx + 16*j;
      base[(size_t)r*G4 + n] = acc[i][j] + (double)bih[n] + (double)bhh[n];
    }
  }
}

// ---------------- fused gates GEMM (f64 acc 8x8, f32-B LDS, BK=32) + LSTM cell ----------------
// block 256 thr. tile: 128 rows x 128 gate-cols (4 gates x 32 units), u0 = blockIdx.y*32.
// col c in [0,128): gate g = c>>5, unit = u0 + (c&31).
// thread (tx,ty): rows r0+ty*8+i; col tx+16*j -> gate j>>1, unit u0+tx+16*(j&1).
__global__ __launch_bounds__(256) void gates_v3(
    const double* __restrict__ hin, double* __restrict__ hout,
    double* __restrict__ cst, const int* __restrict__ idx,
    const double* __restrict__ E, const double* __restrict__ base,
    const float* __restrict__ Whh, const float* __restrict__ Wih,
    const float* __restrict__ wv,
    const float* __restrict__ bih, const float* __restrict__ bhh,
    int nht, int nwt)
{
  __shared__ double Al[32][132];
  __shared__ float  Bl[32][132];
  const int tid = threadIdx.x;
  const int r0 = blockIdx.x * 128;
  const int u0 = blockIdx.y * 32;
  const int tx = tid & 15, ty = tid >> 4;
  double acc[8][8];
  #pragma unroll
  for (int i=0;i<8;++i)
    #pragma unroll
    for (int j=0;j<8;++j) acc[i][j]=0.0;

  const int ra   = tid >> 1, kb16 = (tid & 1) * 16;  // A: row ra, 16 k each
  const int cb   = ra;                                // B: col cb, 16 k each
  const int wrow = (cb >> 5)*HID + u0 + (cb & 31);    // Whh row for B col cb

  for (int t = 0; t < nht + nwt; ++t){
    if (t < nht){
      int k0 = t*32;
      const double* s0 = hin + (size_t)(r0+ra)*HID + k0 + kb16;
      #pragma unroll
      for (int jj=0;jj<8;++jj){
        double2 v = *(const double2*)(s0 + 2*jj);
        Al[kb16+2*jj  ][ra] = v.x;
        Al[kb16+2*jj+1][ra] = v.y;
      }
      const float* s1 = Whh + (size_t)wrow*HID + k0 + kb16;
      #pragma unroll
      for (int jj=0;jj<4;++jj){
        float4 w = *(const float4*)(s1 + 4*jj);
        Bl[kb16+4*jj  ][cb] = w.x;
        Bl[kb16+4*jj+1][cb] = w.y;
        Bl[kb16+4*jj+2][cb] = w.z;
        Bl[kb16+4*jj+3][cb] = w.w;
      }
    } else {
      int k0 = (t - nht)*32;
      #pragma unroll
      for (int j=0;j<16;++j){
        int k = k0 + kb16 + j;
        Al[kb16+j][ra] = (k < WVD) ? (double)wv[(size_t)(r0+ra)*WVD + k] : 0.0;
        Bl[kb16+j][cb] = (k < WVD) ? Wih[(size_t)wrow*IND + EMB + k] : 0.f;
      }
    }
    __syncthreads();
    #pragma unroll
    for (int k=0;k<32;++k){
      double av[8], bv[8];
      #pragma unroll
      for (int i=0;i<8;++i) av[i] = Al[k][ty*8+i];
      #pragma unroll
      for (int j=0;j<8;++j) bv[j] = (double)Bl[k][tx + 16*j];
      #pragma unroll
      for (int i=0;i<8;++i)
        #pragma unroll
        for (int j=0;j<8;++j) acc[i][j] += av[i]*bv[j];
    }
    __syncthreads();
  }

  // epilogue: LSTM cell. thread: rows r0+ty*8+i, units u0+tx, u0+tx+16, all 4 gates.
  #pragma unroll
  for (int i=0;i<8;++i){
    int r = r0 + ty*8 + i;
    int tok = idx[r];
    const double* Er = E + (size_t)tok*G4;
    #pragma unroll
    for (int v=0;v<2;++v){
      int u = u0 + tx + 16*v;
      double pre[4];
      if (base){
        const double* Br = base + (size_t)r*G4;
        #pragma unroll
        for (int g=0;g<4;++g) pre[g] = acc[i][2*g+v] + Er[g*HID+u] + Br[g*HID+u];
      } else {
        #pragma unroll
        for (int g=0;g<4;++g) pre[g] = acc[i][2*g+v] + Er[g*HID+u]
                                     + (double)bih[g*HID+u] + (double)bhh[g*HID+u];
      }
      double co = cst[(size_t)r*HID + u];
      double cn = dsig(pre[1])*co + dsig(pre[0])*dtanh_(pre[2]);
      double hn = dsig(pre[3])*dtanh_(cn);
      cst[(size_t)r*HID + u]  = cn;
      hout[(size_t)r*HID + u] = hn;
    }
  }
}

// ---------------- logits partial GEMM (f64 acc, f32-B LDS, BK=32), split-K=3 ----------------
// grid (R/64, 5, 3). tile 64 rows x 64 cols. partials -> lbuf[r*HID + kk*320 + n].
__global__ __launch_bounds__(256) void logits_v3(
    const double* __restrict__ h, const float* __restrict__ Wlin,
    double* __restrict__ lbuf)
{
  __shared__ double Al[32][68];
  __shared__ float  Bl[32][68];
  const int tid = threadIdx.x;
  const int r0 = blockIdx.x*64, n0 = blockIdx.y*64, kk = blockIdx.z;
  const int kt0 = kk*11;
  const int kt1 = (kk==2) ? 32 : kt0 + 11;
  const int tx = tid & 15, ty = tid >> 4;
  double acc[4][4];
  #pragma unroll
  for (int i=0;i<4;++i)
    #pragma unroll
    for (int j=0;j<4;++j) acc[i][j]=0.0;

  const int ra = tid >> 2, kb8 = (tid & 3) * 8;   // 64 rows/cols, 8 k each
  const int wr = n0 + ra;
  const bool wok = (wr < VOC);
  for (int t = kt0; t < kt1; ++t){
    int k0 = t*32;
    const double* s0 = h + (size_t)(r0+ra)*HID + k0 + kb8;
    #pragma unroll
    for (int jj=0;jj<4;++jj){
      double2 v = *(const double2*)(s0 + 2*jj);
      Al[kb8+2*jj  ][ra] = v.x;
      Al[kb8+2*jj+1][ra] = v.y;
    }
    if (wok){
      const float* s1 = Wlin + (size_t)wr*HID + k0 + kb8;
      float4 w0 = *(const float4*)(s1+0);
      float4 w1 = *(const float4*)(s1+4);
      Bl[kb8+0][ra] = w0.x; Bl[kb8+1][ra] = w0.y;
      Bl[kb8+2][ra] = w0.z; Bl[kb8+3][ra] = w0.w;
      Bl[kb8+4][ra] = w1.x; Bl[kb8+5][ra] = w1.y;
      Bl[kb8+6][ra] = w1.z; Bl[kb8+7][ra] = w1.w;
    } else {
      #pragma unroll
      for (int j=0;j<8;++j) Bl[kb8+j][ra] = 0.f;
    }
    __syncthreads();
    #pragma unroll
    for (int k=0;k<32;++k){
      double av[4], bv[4];
      #pragma unroll
      for (int i=0;i<4;++i) av[i] = Al[k][ty*4+i];
      #pragma unroll
      for (int j=0;j<4;++j) bv[j] = (double)Bl[k][tx+16*j];
      #pragma unroll
      for (int i=0;i<4;++i)
        #pragma unroll
        for (int j=0;j<4;++j) acc[i][j] += av[i]*bv[j];
    }
    __syncthreads();
  }
  #pragma unroll
  for (int i=0;i<4;++i){
    int r = r0 + ty*4 + i;
    #pragma unroll
    for (int j=0;j<4;++j){
      int n = n0 + tx + 16*j;                 // 0..319
      lbuf[(size_t)r*HID + kk*320 + n] = acc[i][j];
    }
  }
}

// ---------------- sum partials + bias, softmax top-1, argmax, next idx ----------------
__global__ __launch_bounds__(256) void argmax_f64(
    const double* __restrict__ lbuf, const float* __restrict__ blin,
    int* __restrict__ idx, float* __restrict__ outp, float* __restrict__ outi)
{
  const int tid = threadIdx.x;
  const int r = blockIdx.x*4 + (tid >> 6);
  const int lane = tid & 63;
  const double* lr = lbuf + (size_t)r*HID;
  double v[5];
  double m = -INFINITY; int am = 0;
  #pragma unroll
  for (int t=0;t<5;++t){
    int col = lane + 64*t;
    if (col < VOC){
      double x = ((lr[col] + lr[320+col]) + lr[640+col]) + (double)blin[col];
      v[t] = x;
      if (x > m){ m = x; am = col; }
    } else v[t] = -INFINITY;
  }
  #pragma unroll
  for (int d=1; d<64; d<<=1){
    double om = __shfl_xor(m, d, 64);
    int   oa = __shfl_xor(am, d, 64);
    if (om > m || (om == m && oa < am)){ m = om; am = oa; }
  }
  double s = 0.0;
  #pragma unroll
  for (int t=0;t<5;++t){
    int col = lane + 64*t;
    if (col < VOC) s += exp(v[t] - m);
  }
  #pragma unroll
  for (int d=1; d<64; d<<=1) s += __shfl_xor(s, d, 64);
  if (lane == 0){
    idx[r]  = am;
    outp[r] = (float)(1.0/s);
    outi[r] = (float)am;
  }
}

// ======================= launch =======================

extern "C" void kernel_launch(void* const* d_in, const int* in_sizes, int n_in,
                              void* d_out, int out_size, void* d_ws, size_t ws_size,
                              hipStream_t stream){
  const float* wv   = (const float*)d_in[0];
  const float* emb  = (const float*)d_in[1];
  const float* Wih  = (const float*)d_in[2];
  const float* Whh  = (const float*)d_in[3];
  const float* bih  = (const float*)d_in[4];
  const float* bhh  = (const float*)d_in[5];
  const float* Wlin = (const float*)d_in[6];
  const float* blin = (const float*)d_in[7];
  float* out = (float*)d_out;

  char* w = (char*)d_ws;
  size_t off = 0;
  auto al = [](size_t b){ return (b + 255) & ~(size_t)255; };
  auto alloc = [&](size_t bytes) -> void* {
    void* p = w + off; off += al(bytes); return p;
  };

  const size_t fixed = al((size_t)VOC*G4*8) + al((size_t)BS*4);

  // tier A: base precompute (preferred). tier B: no base, wv folded into gates.
  int R = 0; bool useBase = false;
  for (int r = 4096; r >= 1024; r >>= 1){
    if (fixed + 3*al((size_t)r*HID*8) + al((size_t)r*G4*8) <= ws_size){ R = r; useBase = true; break; }
  }
  if (!R){
    for (int r = 8192; r >= 256; r >>= 1){
      if (fixed + 3*al((size_t)r*HID*8) <= ws_size){ R = r; break; }
    }
  }
  if (!R) return;

  double* Ed  = (double*)alloc((size_t)VOC*G4*8);
  int*    idx = (int*)   alloc((size_t)BS*4);
  double* h0  = (double*)alloc((size_t)R*HID*8);
  double* h1  = (double*)alloc((size_t)R*HID*8);
  double* cd  = (double*)alloc((size_t)R*HID*8);
  double* base = useBase ? (double*)alloc((size_t)R*G4*8) : nullptr;

  hipMemsetAsync(idx, 0, (size_t)BS*4, stream);
  ekernel_f64<<<dim3(16,17),256,0,stream>>>(emb, Wih, Ed);

  for (int c0 = 0; c0 < BS; c0 += R){
    if (useBase)
      base_v3<<<dim3(R/128, 32),256,0,stream>>>(wv + (size_t)c0*WVD, Wih, bih, bhh, base);
    hipMemsetAsync(cd, 0, (size_t)R*HID*8, stream);
    double* hb[2] = {h0, h1};
    for (int s = 0; s < NST; ++s){
      gates_v3<<<dim3(R/128, 32),256,0,stream>>>(
          hb[s&1], hb[(s+1)&1], cd, idx + c0, Ed, base,
          Whh, Wih, wv + (size_t)c0*WVD, bih, bhh,
          (s==0) ? 0 : HID/32, useBase ? 0 : 10);
      // logits partials written into the now-dead hb[s&1] buffer
      logits_v3<<<dim3(R/64, 5, 3),256,0,stream>>>(
          hb[(s+1)&1], Wlin, hb[s&1]);
      argmax_f64<<<R/4,256,0,stream>>>(
          hb[s&1], blin, idx + c0,
          out + (size_t)s*BS + c0, out + (size_t)NST*BS + (size_t)s*BS + c0);
    }
  }
}